// Round 7
// baseline (9481.660 us; speedup 1.0000x reference)
//
#include <hip/hip_runtime.h>
#include <hip/hip_cooperative_groups.h>

typedef __bf16 bf16;
typedef __bf16 bf16x8 __attribute__((ext_vector_type(8)));
typedef float f32x4 __attribute__((ext_vector_type(4)));
typedef unsigned int u32;
typedef unsigned long long u64;

// Problem dims
#define TT 256
#define NTAGS 50

// Workspace layout (bytes)
#define OFF_WIH   0ull                        // bf16 [1024][1024]
#define OFF_WHH   (OFF_WIH  + 2097152ull)
#define OFF_WCH   (OFF_WHH  + 2097152ull)
#define OFF_WC2H  (OFF_WCH  + 2097152ull)
#define OFF_DW    (OFF_WC2H + 2097152ull)     // bf16 [64][1024] (tags padded to 64)
#define OFF_XW    (OFF_DW   + 131072ull)      // bf16 [16384][1024]  x@Wih^T + b_ih + b_hh
#define OFF_HISTB (OFF_XW   + 33554432ull)    // bf16 [256][64][1024] hy(t+1) at slot t (k_out input)
#define OFF_HB    (OFF_HISTB + 33554432ull)   // bf16 [2][64][1024] h cross-block (slot0 = h0)
#define OFF_CB    (OFF_HB   + 262144ull)      // bf16 [2][64][1024] c cross-block (slot0 = c0)
#define OFF_BAR   (OFF_CB   + 262144ull)      // u32 [4 groups][16 blocks][32]: 1 flag/128B line
#define N_FLAG_WORDS (4 * 16 * 32)
// total ~72.6 MB

// Agent-scope relaxed (L1/L2-bypassing, meet-at-L3) accessors — r5-proven.
__device__ __forceinline__ u64 cohload(const u64* p) {
  return __hip_atomic_load(p, __ATOMIC_RELAXED, __HIP_MEMORY_SCOPE_AGENT);
}
__device__ __forceinline__ void cohstore(u64* p, u64 v) {
  __hip_atomic_store(p, v, __ATOMIC_RELAXED, __HIP_MEMORY_SCOPE_AGENT);
}
__device__ __forceinline__ bf16x8 cohload_v8(const bf16* p) {
  union { u64 q[2]; bf16x8 v; } u;
  const u64* q = (const u64*)p;
  u.q[0] = cohload(q);
  u.q[1] = cohload(q + 1);
  return u.v;
}

// ---------------- prep: weights->bf16, h0/c0 slot0 init, barrier flags=0 ----------------
__global__ void k_prep(const float* __restrict__ wih, const float* __restrict__ whh,
                       const float* __restrict__ wch, const float* __restrict__ wc2h,
                       const float* __restrict__ dw, const float* __restrict__ h0,
                       const float* __restrict__ c0, char* __restrict__ ws) {
  const long N_W = 4194304, N_DW = 65536, N_S = 65536;
  const long TOT = N_W + N_DW + 2 * N_S + N_FLAG_WORDS;
  long stride = (long)gridDim.x * blockDim.x;
  for (long idx = (long)blockIdx.x * blockDim.x + threadIdx.x; idx < TOT; idx += stride) {
    if (idx < N_W) {
      long m = idx >> 20, e = idx & 1048575;
      const float* s = (m == 0) ? wih : (m == 1) ? whh : (m == 2) ? wch : wc2h;
      ((bf16*)(ws + OFF_WIH))[idx] = (bf16)s[e];
    } else if (idx < N_W + N_DW) {
      long j = idx - N_W; long r = j >> 10, e = j & 1023;
      ((bf16*)(ws + OFF_DW))[j] = (bf16)((r < NTAGS) ? dw[r * 1024 + e] : 0.f);
    } else if (idx < N_W + N_DW + N_S) {          // HB slot0 = h0
      long j = idx - N_W - N_DW;
      ((bf16*)(ws + OFF_HB))[j] = (bf16)h0[j];
    } else if (idx < N_W + N_DW + 2 * N_S) {      // CB slot0 = c0
      long j = idx - N_W - N_DW - N_S;
      ((bf16*)(ws + OFF_CB))[j] = (bf16)c0[j];
    } else {                                      // flags = 0 (replay safety)
      long j = idx - N_W - N_DW - 2 * N_S;
      ((u32*)(ws + OFF_BAR))[j] = 0u;
    }
  }
}

// ---------------- XW = emb[X] @ Wih^T + b_ih + b_hh  (gather fused) ----------------
__global__ __launch_bounds__(256) void k_xw(const int* __restrict__ X,
                                            const float* __restrict__ emb,
                                            const float* __restrict__ b_ih,
                                            const float* __restrict__ b_hh,
                                            char* __restrict__ ws) {
  const bf16* wih = (const bf16*)(ws + OFF_WIH);
  bf16* xw = (bf16*)(ws + OFF_XW);
  int l = threadIdx.x & 63, wv = threadIdx.x >> 6;
  int i0 = blockIdx.x * 64 + wv * 16;
  int h0 = blockIdx.y * 64;
  const float* ap = emb + (long)X[i0 + (l & 15)] * 1024 + ((l >> 4) * 8);
  const bf16* bp = wih + (long)(h0 + (l & 15)) * 1024 + ((l >> 4) * 8);
  f32x4 zero = {0.f, 0.f, 0.f, 0.f};
  f32x4 acc[4] = {zero, zero, zero, zero};
  for (int k = 0; k < 1024; k += 32) {
    f32x4 f0 = *(const f32x4*)(ap + k);
    f32x4 f1 = *(const f32x4*)(ap + k + 4);
    bf16x8 a;
#pragma unroll
    for (int q = 0; q < 4; ++q) { a[q] = (bf16)f0[q]; a[4 + q] = (bf16)f1[q]; }
#pragma unroll
    for (int j = 0; j < 4; ++j) {
      bf16x8 b = *(const bf16x8*)(bp + j * 16 * 1024 + k);
      acc[j] = __builtin_amdgcn_mfma_f32_16x16x32_bf16(a, b, acc[j], 0, 0, 0);
    }
  }
#pragma unroll
  for (int j = 0; j < 4; ++j)
#pragma unroll
    for (int r = 0; r < 4; ++r) {
      int row = i0 + (l >> 4) * 4 + r;
      int col = h0 + j * 16 + (l & 15);
      xw[(long)row * 1024 + col] = (bf16)(acc[j][r] + b_ih[col] + b_hh[col]);
    }
}

// ---------------- recurrence: 4 groups x 16 fat blocks (1024 thr) ----------------
// Group g owns batch rows [16g,16g+16); block j owns h-cols [64j,64j+64).
// 16 waves = 4 col-subtiles (cg) x 4 K-slices (kg, 256 each).
// Sync cohort per group = 16 blocks (was 64): publish 2KB tile -> vmcnt(0) ->
// flag -> poll 16 flag lines -> consumers cohload. All data agent-scope relaxed.
// blockIdx swizzle: g=idx>>4, j=idx&15 so 4 groups' same-j blocks share an XCD
// (perf-only heuristic: 4x weight reuse in that XCD's L2).
__global__ __launch_bounds__(1024, 1) void k_rnn(const float* __restrict__ b_ch,
                                                 const float* __restrict__ b_c2h,
                                                 const float* __restrict__ c0,
                                                 char* __restrict__ ws) {
  const bf16* xw = (const bf16*)(ws + OFF_XW);
  bf16* histb = (bf16*)(ws + OFF_HISTB);
  bf16* HB = (bf16*)(ws + OFF_HB);
  bf16* CB = (bf16*)(ws + OFF_CB);
  int g = blockIdx.x >> 4, j = blockIdx.x & 15;
  u32* flags = (u32*)(ws + OFF_BAR) + g * 16 * 32;

  int tid = threadIdx.x;
  int w = tid >> 6, l = tid & 63;
  int cg = w & 3, kg = w >> 2;
  int b0 = g * 16, h0b = j * 64;

  // elementwise mapping: thread (w,l) owns element (row=w, col=l) of the 16x64 tile
  int eoff = (b0 + w) * 1024 + h0b + l;

  __shared__ float red[4][4][2][256];   // [cg][kg][pre/cg][16x16 tile]
  __shared__ bf16 xfer[1024];           // outgoing 16x64 tile

  int lane_r = l & 15;
  int koff = kg * 256 + ((l >> 4) * 8);
  long arow = (long)(b0 + lane_r) * 1024 + koff;        // A-frag source offset
  long wrow = (long)(h0b + cg * 16 + lane_r) * 1024 + koff;  // B-frag (weight) offset
  const bf16* whh_p  = (const bf16*)(ws + OFF_WHH)  + wrow;
  const bf16* wch_p  = (const bf16*)(ws + OFF_WCH)  + wrow;
  const bf16* wc2h_p = (const bf16*)(ws + OFF_WC2H) + wrow;

  float bch_v = b_ch[h0b + l], bc2h_v = b_c2h[h0b + l];
  float c_reg = c0[eoff];
  f32x4 zero = {0.f, 0.f, 0.f, 0.f};

  for (int t = 0; t < TT; ++t) {
    long slot0 = (long)(t & 1) * 65536, slot1 = (long)((t + 1) & 1) * 65536;
    float xwv = (float)xw[(long)t * 65536 + eoff];
    u32 tkA = 2u * t + 1u, tkB = 2u * t + 2u;

    // ---- phase A: pre = h(t)@Whh (+xw), cg = c(t)@Wch
    f32x4 ap_ = zero, ac_ = zero;
#pragma unroll
    for (int kk = 0; kk < 8; ++kk) {
      bf16x8 a1 = cohload_v8(HB + slot0 + arow + kk * 32);
      ap_ = __builtin_amdgcn_mfma_f32_16x16x32_bf16(a1, *(const bf16x8*)(whh_p + kk * 32), ap_, 0, 0, 0);
      bf16x8 a2 = cohload_v8(CB + slot0 + arow + kk * 32);
      ac_ = __builtin_amdgcn_mfma_f32_16x16x32_bf16(a2, *(const bf16x8*)(wch_p + kk * 32), ac_, 0, 0, 0);
    }
#pragma unroll
    for (int r = 0; r < 4; ++r) {
      int ei = ((l >> 4) * 4 + r) * 16 + (l & 15);
      red[cg][kg][0][ei] = ap_[r];
      red[cg][kg][1][ei] = ac_[r];
    }
    __syncthreads();
    int ei_e = w * 16 + (l & 15), cg_e = l >> 4;
    float pre = red[cg_e][0][0][ei_e] + red[cg_e][1][0][ei_e]
              + red[cg_e][2][0][ei_e] + red[cg_e][3][0][ei_e] + xwv;
    float cgm = red[cg_e][0][1][ei_e] + red[cg_e][1][1][ei_e]
              + red[cg_e][2][1][ei_e] + red[cg_e][3][1][ei_e] + bch_v;
    float gif = 1.f / (1.f + expf(-(pre + cgm)));
    float cy = gif * (c_reg + tanhf(pre));
    c_reg = cy;
    xfer[tid] = (bf16)cy;
    __syncthreads();                 // xfer ready; red reads done
    if (tid < 64) {                  // wave 0 publishes the 2KB tile (4 x u64 per lane)
#pragma unroll
      for (int q = 0; q < 4; ++q) {
        int wi = tid * 4 + q, trow = wi >> 4, tpart = wi & 15;
        cohstore((u64*)(CB + slot1 + (long)(b0 + trow) * 1024 + h0b) + tpart,
                 ((u64*)xfer)[wi]);
      }
      asm volatile("s_waitcnt vmcnt(0)" ::: "memory");
      if (tid == 0)
        __hip_atomic_store(&flags[j * 32], tkA, __ATOMIC_RELAXED, __HIP_MEMORY_SCOPE_AGENT);
      const u32* my = &flags[(tid & 15) * 32];
      while (!__all(__hip_atomic_load(my, __ATOMIC_RELAXED, __HIP_MEMORY_SCOPE_AGENT) >= tkA))
        __builtin_amdgcn_s_sleep(1);
    }
    asm volatile("" ::: "memory");
    __syncthreads();

    // ---- phase B: o = cy(t+1)@Wc2h
    f32x4 ao = zero;
#pragma unroll
    for (int kk = 0; kk < 8; ++kk) {
      bf16x8 a3 = cohload_v8(CB + slot1 + arow + kk * 32);
      ao = __builtin_amdgcn_mfma_f32_16x16x32_bf16(a3, *(const bf16x8*)(wc2h_p + kk * 32), ao, 0, 0, 0);
    }
#pragma unroll
    for (int r = 0; r < 4; ++r)
      red[cg][kg][0][((l >> 4) * 4 + r) * 16 + (l & 15)] = ao[r];
    __syncthreads();
    float o = red[cg_e][0][0][ei_e] + red[cg_e][1][0][ei_e]
            + red[cg_e][2][0][ei_e] + red[cg_e][3][0][ei_e] + bc2h_v;
    float og = 1.f / (1.f + expf(-(pre + o)));
    bf16 hb = (bf16)(og * tanhf(cy));
    histb[(long)t * 65536 + eoff] = hb;      // plain store for k_out
    xfer[tid] = hb;
    __syncthreads();
    if (t < TT - 1) {
      if (tid < 64) {
#pragma unroll
        for (int q = 0; q < 4; ++q) {
          int wi = tid * 4 + q, trow = wi >> 4, tpart = wi & 15;
          cohstore((u64*)(HB + slot1 + (long)(b0 + trow) * 1024 + h0b) + tpart,
                   ((u64*)xfer)[wi]);
        }
        asm volatile("s_waitcnt vmcnt(0)" ::: "memory");
        if (tid == 0)
          __hip_atomic_store(&flags[j * 32], tkB, __ATOMIC_RELAXED, __HIP_MEMORY_SCOPE_AGENT);
        const u32* my = &flags[(tid & 15) * 32];
        while (!__all(__hip_atomic_load(my, __ATOMIC_RELAXED, __HIP_MEMORY_SCOPE_AGENT) >= tkB))
          __builtin_amdgcn_s_sleep(1);
      }
      asm volatile("" ::: "memory");
      __syncthreads();
    }
  }
}

// ---------------- dense + softmax ----------------
__global__ __launch_bounds__(256) void k_out(const float* __restrict__ dense_b,
                                             const char* __restrict__ ws,
                                             float* __restrict__ out) {
  const bf16* h  = (const bf16*)(ws + OFF_HISTB);  // slot t = hy at step t
  const bf16* dw = (const bf16*)(ws + OFF_DW);
  int l = threadIdx.x & 63, wv = threadIdx.x >> 6;
  int i0 = blockIdx.x * 64 + wv * 16;
  const bf16* ap = h  + (long)(i0 + (l & 15)) * 1024 + ((l >> 4) * 8);
  const bf16* bp = dw + (long)(l & 15) * 1024 + ((l >> 4) * 8);
  f32x4 zero = {0.f, 0.f, 0.f, 0.f};
  f32x4 acc[4] = {zero, zero, zero, zero};
  for (int k = 0; k < 1024; k += 32) {
    bf16x8 a = *(const bf16x8*)(ap + k);
#pragma unroll
    for (int j = 0; j < 4; ++j) {
      bf16x8 b = *(const bf16x8*)(bp + j * 16 * 1024 + k);
      acc[j] = __builtin_amdgcn_mfma_f32_16x16x32_bf16(a, b, acc[j], 0, 0, 0);
    }
  }
  int tag0 = l & 15;
#pragma unroll
  for (int r = 0; r < 4; ++r) {
    int row = i0 + (l >> 4) * 4 + r;
    float lg[4], ex[4];
    float mx = -1e30f;
#pragma unroll
    for (int j = 0; j < 4; ++j) {
      int tag = j * 16 + tag0;
      lg[j] = (tag < NTAGS) ? (acc[j][r] + dense_b[tag]) : -1e30f;
      mx = fmaxf(mx, lg[j]);
    }
    for (int m = 1; m < 16; m <<= 1) mx = fmaxf(mx, __shfl_xor(mx, m, 64));
    float s = 0.f;
#pragma unroll
    for (int j = 0; j < 4; ++j) {
      int tag = j * 16 + tag0;
      ex[j] = (tag < NTAGS) ? expf(lg[j] - mx) : 0.f;
      s += ex[j];
    }
    for (int m = 1; m < 16; m <<= 1) s += __shfl_xor(s, m, 64);
    float inv = 1.f / s;
#pragma unroll
    for (int j = 0; j < 4; ++j) {
      int tag = j * 16 + tag0;
      if (tag < NTAGS) out[(long)row * 50 + tag] = ex[j] * inv;
    }
  }
}

extern "C" void kernel_launch(void* const* d_in, const int* in_sizes, int n_in,
                              void* d_out, int out_size, void* d_ws, size_t ws_size,
                              hipStream_t stream) {
  const int*   X        = (const int*)d_in[0];
  // d_in[1] = lengths (unused; all == T)
  const float* embedding = (const float*)d_in[2];
  const float* w_ih  = (const float*)d_in[3];
  const float* w_hh  = (const float*)d_in[4];
  const float* w_ch  = (const float*)d_in[5];
  const float* w_c2h = (const float*)d_in[6];
  const float* b_ih  = (const float*)d_in[7];
  const float* b_hh  = (const float*)d_in[8];
  const float* b_ch  = (const float*)d_in[9];
  const float* b_c2h = (const float*)d_in[10];
  const float* dense_w = (const float*)d_in[11];
  const float* dense_b = (const float*)d_in[12];
  const float* h0 = (const float*)d_in[13];
  const float* c0 = (const float*)d_in[14];
  char* ws = (char*)d_ws;
  float* out = (float*)d_out;

  k_prep<<<2048, 256, 0, stream>>>(w_ih, w_hh, w_ch, w_c2h, dense_w, h0, c0, ws);
  k_xw<<<dim3(256, 16), 256, 0, stream>>>(X, embedding, b_ih, b_hh, ws);

  void* args[] = {(void*)&b_ch, (void*)&b_c2h, (void*)&c0, (void*)&ws};
  hipLaunchCooperativeKernel((const void*)k_rnn, dim3(64), dim3(1024), args, 0, stream);

  k_out<<<256, 256, 0, stream>>>(dense_b, ws, out);
}

// Round 8
// 2291.837 us; speedup vs baseline: 4.1371x; 4.1371x over previous
//
#include <hip/hip_runtime.h>
#include <hip/hip_cooperative_groups.h>

typedef __bf16 bf16;
typedef __bf16 bf16x8 __attribute__((ext_vector_type(8)));
typedef float f32x4 __attribute__((ext_vector_type(4)));
typedef unsigned int u32;
typedef unsigned long long u64;
typedef unsigned int u32x4 __attribute__((ext_vector_type(4)));

// Problem dims
#define TT 256
#define NTAGS 50

// Workspace layout (bytes)
#define OFF_WIH   0ull                        // bf16 [1024][1024]
#define OFF_WHH   (OFF_WIH  + 2097152ull)
#define OFF_WCH   (OFF_WHH  + 2097152ull)
#define OFF_WC2H  (OFF_WCH  + 2097152ull)
#define OFF_DW    (OFF_WC2H + 2097152ull)     // bf16 [64][1024] (tags padded to 64)
#define OFF_XW    (OFF_DW   + 131072ull)      // bf16 [16384][1024]  x@Wih^T + b_ih + b_hh
#define OFF_HISTB (OFF_XW   + 33554432ull)    // bf16 [256][64][1024] hy at step t (k_out input)
#define OFF_HB    (OFF_HISTB + 33554432ull)   // bf16 [2][64][1024] h cross-block (slot0 = h0)
#define OFF_CB    (OFF_HB   + 262144ull)      // bf16 [2][64][1024] c cross-block (slot0 = c0)
#define OFF_BAR   (OFF_CB   + 262144ull)      // u32 [4][64][32]: 1 flag per 128B line
#define N_FLAG_WORDS (4 * 64 * 32)
// total ~72.6 MB

// Agent-scope relaxed (L1/L2-bypassing, meet-at-L3) accessors — r5-proven.
__device__ __forceinline__ u64 cohload(const u64* p) {
  return __hip_atomic_load(p, __ATOMIC_RELAXED, __HIP_MEMORY_SCOPE_AGENT);
}
__device__ __forceinline__ void cohstore(u64* p, u64 v) {
  __hip_atomic_store(p, v, __ATOMIC_RELAXED, __HIP_MEMORY_SCOPE_AGENT);
}
__device__ __forceinline__ bf16x8 cohload_v8(const bf16* p) {
  union { u64 q[2]; bf16x8 v; } u;
  const u64* q = (const u64*)p;
  u.q[0] = cohload(q);
  u.q[1] = cohload(q + 1);
  return u.v;
}
__device__ __forceinline__ u32x4 cohload_q4(const bf16* p) {
  union { u64 q[2]; u32x4 v; } u;
  const u64* q = (const u64*)p;
  u.q[0] = cohload(q);
  u.q[1] = cohload(q + 1);
  return u.v;
}

// ---------------- prep: weights->bf16, h0/c0 slot0 init, barrier flags=0 ----------------
__global__ void k_prep(const float* __restrict__ wih, const float* __restrict__ whh,
                       const float* __restrict__ wch, const float* __restrict__ wc2h,
                       const float* __restrict__ dw, const float* __restrict__ h0,
                       const float* __restrict__ c0, char* __restrict__ ws) {
  const long N_W = 4194304, N_DW = 65536, N_S = 65536;
  const long TOT = N_W + N_DW + 2 * N_S + N_FLAG_WORDS;
  long stride = (long)gridDim.x * blockDim.x;
  for (long idx = (long)blockIdx.x * blockDim.x + threadIdx.x; idx < TOT; idx += stride) {
    if (idx < N_W) {
      long m = idx >> 20, e = idx & 1048575;
      const float* s = (m == 0) ? wih : (m == 1) ? whh : (m == 2) ? wch : wc2h;
      ((bf16*)(ws + OFF_WIH))[idx] = (bf16)s[e];
    } else if (idx < N_W + N_DW) {
      long j = idx - N_W; long r = j >> 10, e = j & 1023;
      ((bf16*)(ws + OFF_DW))[j] = (bf16)((r < NTAGS) ? dw[r * 1024 + e] : 0.f);
    } else if (idx < N_W + N_DW + N_S) {          // HB slot0 = h0
      long j = idx - N_W - N_DW;
      ((bf16*)(ws + OFF_HB))[j] = (bf16)h0[j];
    } else if (idx < N_W + N_DW + 2 * N_S) {      // CB slot0 = c0
      long j = idx - N_W - N_DW - N_S;
      ((bf16*)(ws + OFF_CB))[j] = (bf16)c0[j];
    } else {                                      // flags = 0 (replay safety)
      long j = idx - N_W - N_DW - 2 * N_S;
      ((u32*)(ws + OFF_BAR))[j] = 0u;
    }
  }
}

// ---------------- XW = emb[X] @ Wih^T + b_ih + b_hh  (gather fused) ----------------
__global__ __launch_bounds__(256) void k_xw(const int* __restrict__ X,
                                            const float* __restrict__ emb,
                                            const float* __restrict__ b_ih,
                                            const float* __restrict__ b_hh,
                                            char* __restrict__ ws) {
  const bf16* wih = (const bf16*)(ws + OFF_WIH);
  bf16* xw = (bf16*)(ws + OFF_XW);
  int l = threadIdx.x & 63, wv = threadIdx.x >> 6;
  int i0 = blockIdx.x * 64 + wv * 16;
  int h0 = blockIdx.y * 64;
  const float* ap = emb + (long)X[i0 + (l & 15)] * 1024 + ((l >> 4) * 8);
  const bf16* bp = wih + (long)(h0 + (l & 15)) * 1024 + ((l >> 4) * 8);
  f32x4 zero = {0.f, 0.f, 0.f, 0.f};
  f32x4 acc[4] = {zero, zero, zero, zero};
  for (int k = 0; k < 1024; k += 32) {
    f32x4 f0 = *(const f32x4*)(ap + k);
    f32x4 f1 = *(const f32x4*)(ap + k + 4);
    bf16x8 a;
#pragma unroll
    for (int q = 0; q < 4; ++q) { a[q] = (bf16)f0[q]; a[4 + q] = (bf16)f1[q]; }
#pragma unroll
    for (int j = 0; j < 4; ++j) {
      bf16x8 b = *(const bf16x8*)(bp + j * 16 * 1024 + k);
      acc[j] = __builtin_amdgcn_mfma_f32_16x16x32_bf16(a, b, acc[j], 0, 0, 0);
    }
  }
#pragma unroll
  for (int j = 0; j < 4; ++j)
#pragma unroll
    for (int r = 0; r < 4; ++r) {
      int row = i0 + (l >> 4) * 4 + r;
      int col = h0 + j * 16 + (l & 15);
      xw[(long)row * 1024 + col] = (bf16)(acc[j][r] + b_ih[col] + b_hh[col]);
    }
}

// ---------------- recurrence: 4 indep batch-groups x 64 blocks (r5 skeleton) ----------------
// group g = blockIdx&3 owns batch rows [16g,16g+16); block j = blockIdx>>2 owns h-slice
// [16j,16j+16). 4 waves K-split (256 each). Changes vs r5:
//  (1) weights pinned in VGPRs with IN-LOOP asm (defeats rematerialization),
//  (2) phase-B c fragments carried in registers into next phase A (halves A's loads),
//  (3) histb store moved off the vmcnt-drain critical path.
__global__ __launch_bounds__(256, 1) void k_rnn(const float* __restrict__ b_ch,
                                                const float* __restrict__ b_c2h,
                                                const float* __restrict__ c0,
                                                char* __restrict__ ws) {
  const bf16* xw = (const bf16*)(ws + OFF_XW);
  bf16* histb = (bf16*)(ws + OFF_HISTB);
  bf16* HB = (bf16*)(ws + OFF_HB);
  bf16* CB = (bf16*)(ws + OFF_CB);
  int g = blockIdx.x & 3, j = blockIdx.x >> 2;
  u32* flags = (u32*)(ws + OFF_BAR) + g * 64 * 32;

  int l = threadIdx.x & 63, wv = threadIdx.x >> 6;
  int b0 = g * 16, h0b = j * 16;
  int e = threadIdx.x;
  int eoff = (b0 + (e >> 4)) * 1024 + h0b + (e & 15);
  int gh = h0b + (e & 15);

  __shared__ float red[4][2][256];
  __shared__ bf16 xfer[256];   // 16x16 outgoing tile staging

  int lane_r = l & 15;
  int koff = wv * 256 + ((l >> 4) * 8);
  long arow = (long)(b0 + lane_r) * 1024 + koff;

  // weight fragments -> registers (96 VGPRs of bf16), plus rolling c fragments.
  u32x4 whh_r[8], wch_r[8], wc2h_r[8], cfr[8];
  {
    const bf16* p1 = (const bf16*)(ws + OFF_WHH)  + (long)(h0b + lane_r) * 1024 + koff;
    const bf16* p2 = (const bf16*)(ws + OFF_WCH)  + (long)(h0b + lane_r) * 1024 + koff;
    const bf16* p3 = (const bf16*)(ws + OFF_WC2H) + (long)(h0b + lane_r) * 1024 + koff;
#pragma unroll
    for (int kk = 0; kk < 8; ++kk) {
      whh_r[kk]  = *(const u32x4*)(p1 + kk * 32);
      wch_r[kk]  = *(const u32x4*)(p2 + kk * 32);
      wc2h_r[kk] = *(const u32x4*)(p3 + kk * 32);
      cfr[kk] = cohload_q4(CB + arow + kk * 32);   // c(0) from slot0
    }
  }

  float bch_v = b_ch[gh], bc2h_v = b_c2h[gh];
  float c_reg = c0[eoff];
  f32x4 zero = {0.f, 0.f, 0.f, 0.f};

  for (int t = 0; t < TT; ++t) {
    // In-loop pins: the empty asm "modifies" the frags every iteration, so the
    // compiler must keep them resident in VGPRs (cannot re-load from memory).
    asm volatile("" : "+v"(whh_r[0]), "+v"(whh_r[1]), "+v"(whh_r[2]), "+v"(whh_r[3]),
                      "+v"(whh_r[4]), "+v"(whh_r[5]), "+v"(whh_r[6]), "+v"(whh_r[7]),
                      "+v"(wch_r[0]), "+v"(wch_r[1]), "+v"(wch_r[2]), "+v"(wch_r[3]),
                      "+v"(wch_r[4]), "+v"(wch_r[5]), "+v"(wch_r[6]), "+v"(wch_r[7]));
    asm volatile("" : "+v"(wc2h_r[0]), "+v"(wc2h_r[1]), "+v"(wc2h_r[2]), "+v"(wc2h_r[3]),
                      "+v"(wc2h_r[4]), "+v"(wc2h_r[5]), "+v"(wc2h_r[6]), "+v"(wc2h_r[7]));
    asm volatile("" : "+v"(cfr[0]), "+v"(cfr[1]), "+v"(cfr[2]), "+v"(cfr[3]),
                      "+v"(cfr[4]), "+v"(cfr[5]), "+v"(cfr[6]), "+v"(cfr[7]));

    long slot1 = (long)((t + 1) & 1) * 65536;
    float xwv = (float)xw[(long)t * 65536 + eoff];   // off the L3 poll path (L2-cached)
    u32 tkA = 2u * t + 1u, tkB = 2u * t + 2u;
    const bf16* hx = HB + (long)(t & 1) * 65536;

    // ---- phase A: pre = h(t)@Whh (+xw), cg = c(t)@Wch (c frags already in regs)
    f32x4 ap_ = zero, ac_ = zero;
#pragma unroll
    for (int kk = 0; kk < 8; ++kk) {
      bf16x8 a1 = cohload_v8(hx + arow + kk * 32);
      ap_ = __builtin_amdgcn_mfma_f32_16x16x32_bf16(
          a1, __builtin_bit_cast(bf16x8, whh_r[kk]), ap_, 0, 0, 0);
      ac_ = __builtin_amdgcn_mfma_f32_16x16x32_bf16(
          __builtin_bit_cast(bf16x8, cfr[kk]), __builtin_bit_cast(bf16x8, wch_r[kk]), ac_, 0, 0, 0);
    }
#pragma unroll
    for (int r = 0; r < 4; ++r) {
      int ei = ((l >> 4) * 4 + r) * 16 + (l & 15);
      red[wv][0][ei] = ap_[r];
      red[wv][1][ei] = ac_[r];
    }
    __syncthreads();
    float pre = red[0][0][e] + red[1][0][e] + red[2][0][e] + red[3][0][e] + xwv;
    float cgm = red[0][1][e] + red[1][1][e] + red[2][1][e] + red[3][1][e] + bch_v;
    float gif = 1.f / (1.f + expf(-(pre + cgm)));
    float cy = gif * (c_reg + tanhf(pre));
    c_reg = cy;
    xfer[e] = (bf16)cy;
    __syncthreads();                    // xfer ready; red reads done
    if (e < 64)
      cohstore((u64*)(CB + slot1 + (long)(b0 + (e >> 2)) * 1024 + h0b) + (e & 3),
               ((u64*)xfer)[e]);
    asm volatile("s_waitcnt vmcnt(0)" ::: "memory");   // tile stores ack'd @L3
    if (e == 0)
      __hip_atomic_store(&flags[j * 32], tkA, __ATOMIC_RELAXED, __HIP_MEMORY_SCOPE_AGENT);
    if (e < 64) {
      const u32* my = &flags[e * 32];
      while (!__all(__hip_atomic_load(my, __ATOMIC_RELAXED, __HIP_MEMORY_SCOPE_AGENT) >= tkA))
        __builtin_amdgcn_s_sleep(1);
    }
    asm volatile("" ::: "memory");
    __syncthreads();

    // ---- phase B: o = cy(t+1)@Wc2h; keep cy frags for next step's phase A
    f32x4 ao = zero;
#pragma unroll
    for (int kk = 0; kk < 8; ++kk) {
      cfr[kk] = cohload_q4(CB + slot1 + arow + kk * 32);
      ao = __builtin_amdgcn_mfma_f32_16x16x32_bf16(
          __builtin_bit_cast(bf16x8, cfr[kk]), __builtin_bit_cast(bf16x8, wc2h_r[kk]), ao, 0, 0, 0);
    }
#pragma unroll
    for (int r = 0; r < 4; ++r)
      red[wv][0][((l >> 4) * 4 + r) * 16 + (l & 15)] = ao[r];
    __syncthreads();
    float o = red[0][0][e] + red[1][0][e] + red[2][0][e] + red[3][0][e] + bc2h_v;
    float og = 1.f / (1.f + expf(-(pre + o)));
    bf16 hb = (bf16)(og * tanhf(cy));
    xfer[e] = hb;
    __syncthreads();
    if (t < TT - 1) {
      if (e < 64)
        cohstore((u64*)(HB + slot1 + (long)(b0 + (e >> 2)) * 1024 + h0b) + (e & 3),
                 ((u64*)xfer)[e]);
      asm volatile("s_waitcnt vmcnt(0)" ::: "memory");
      if (e == 0)
        __hip_atomic_store(&flags[j * 32], tkB, __ATOMIC_RELAXED, __HIP_MEMORY_SCOPE_AGENT);
      if (e < 64) {
        const u32* my = &flags[e * 32];
        while (!__all(__hip_atomic_load(my, __ATOMIC_RELAXED, __HIP_MEMORY_SCOPE_AGENT) >= tkB))
          __builtin_amdgcn_s_sleep(1);
      }
      asm volatile("" ::: "memory");
      __syncthreads();
    }
    histb[(long)t * 65536 + eoff] = hb;   // off the critical path (after barrier)
  }
}

// ---------------- dense + softmax ----------------
__global__ __launch_bounds__(256) void k_out(const float* __restrict__ dense_b,
                                             const char* __restrict__ ws,
                                             float* __restrict__ out) {
  const bf16* h  = (const bf16*)(ws + OFF_HISTB);  // slot t = hy at step t
  const bf16* dw = (const bf16*)(ws + OFF_DW);
  int l = threadIdx.x & 63, wv = threadIdx.x >> 6;
  int i0 = blockIdx.x * 64 + wv * 16;
  const bf16* ap = h  + (long)(i0 + (l & 15)) * 1024 + ((l >> 4) * 8);
  const bf16* bp = dw + (long)(l & 15) * 1024 + ((l >> 4) * 8);
  f32x4 zero = {0.f, 0.f, 0.f, 0.f};
  f32x4 acc[4] = {zero, zero, zero, zero};
  for (int k = 0; k < 1024; k += 32) {
    bf16x8 a = *(const bf16x8*)(ap + k);
#pragma unroll
    for (int j = 0; j < 4; ++j) {
      bf16x8 b = *(const bf16x8*)(bp + j * 16 * 1024 + k);
      acc[j] = __builtin_amdgcn_mfma_f32_16x16x32_bf16(a, b, acc[j], 0, 0, 0);
    }
  }
  int tag0 = l & 15;
#pragma unroll
  for (int r = 0; r < 4; ++r) {
    int row = i0 + (l >> 4) * 4 + r;
    float lg[4], ex[4];
    float mx = -1e30f;
#pragma unroll
    for (int j = 0; j < 4; ++j) {
      int tag = j * 16 + tag0;
      lg[j] = (tag < NTAGS) ? (acc[j][r] + dense_b[tag]) : -1e30f;
      mx = fmaxf(mx, lg[j]);
    }
    for (int m = 1; m < 16; m <<= 1) mx = fmaxf(mx, __shfl_xor(mx, m, 64));
    float s = 0.f;
#pragma unroll
    for (int j = 0; j < 4; ++j) {
      int tag = j * 16 + tag0;
      ex[j] = (tag < NTAGS) ? expf(lg[j] - mx) : 0.f;
      s += ex[j];
    }
    for (int m = 1; m < 16; m <<= 1) s += __shfl_xor(s, m, 64);
    float inv = 1.f / s;
#pragma unroll
    for (int j = 0; j < 4; ++j) {
      int tag = j * 16 + tag0;
      if (tag < NTAGS) out[(long)row * 50 + tag] = ex[j] * inv;
    }
  }
}

extern "C" void kernel_launch(void* const* d_in, const int* in_sizes, int n_in,
                              void* d_out, int out_size, void* d_ws, size_t ws_size,
                              hipStream_t stream) {
  const int*   X        = (const int*)d_in[0];
  // d_in[1] = lengths (unused; all == T)
  const float* embedding = (const float*)d_in[2];
  const float* w_ih  = (const float*)d_in[3];
  const float* w_hh  = (const float*)d_in[4];
  const float* w_ch  = (const float*)d_in[5];
  const float* w_c2h = (const float*)d_in[6];
  const float* b_ih  = (const float*)d_in[7];
  const float* b_hh  = (const float*)d_in[8];
  const float* b_ch  = (const float*)d_in[9];
  const float* b_c2h = (const float*)d_in[10];
  const float* dense_w = (const float*)d_in[11];
  const float* dense_b = (const float*)d_in[12];
  const float* h0 = (const float*)d_in[13];
  const float* c0 = (const float*)d_in[14];
  char* ws = (char*)d_ws;
  float* out = (float*)d_out;

  k_prep<<<2048, 256, 0, stream>>>(w_ih, w_hh, w_ch, w_c2h, dense_w, h0, c0, ws);
  k_xw<<<dim3(256, 16), 256, 0, stream>>>(X, embedding, b_ih, b_hh, ws);

  void* args[] = {(void*)&b_ch, (void*)&b_c2h, (void*)&c0, (void*)&ws};
  hipLaunchCooperativeKernel((const void*)k_rnn, dim3(256), dim3(256), args, 0, stream);

  k_out<<<256, 256, 0, stream>>>(dense_b, ws, out);
}

// Round 10
// 2282.334 us; speedup vs baseline: 4.1544x; 1.0042x over previous
//
#include <hip/hip_runtime.h>
#include <hip/hip_cooperative_groups.h>

typedef __bf16 bf16;
typedef __bf16 bf16x8 __attribute__((ext_vector_type(8)));
typedef float f32x4 __attribute__((ext_vector_type(4)));
typedef unsigned int u32;
typedef unsigned long long u64;
typedef unsigned int u32x4 __attribute__((ext_vector_type(4)));

// Problem dims
#define TT 256
#define NTAGS 50

// Workspace layout (bytes) — r8-proven
#define OFF_WIH   0ull                        // bf16 [1024][1024]
#define OFF_WHH   2097152ull
#define OFF_WCH   4194304ull
#define OFF_WC2H  6291456ull
#define OFF_DW    8388608ull                  // bf16 [64][1024] (tags padded to 64)
#define OFF_XW    8519680ull                  // bf16 [16384][1024]
#define OFF_HISTB 42074112ull                 // bf16 [256][64][1024] hy at step t (k_out input)
#define OFF_HB    75628544ull                 // bf16 [2][64][1024] h cross-block (slot0 = h0)
#define OFF_CB    75890688ull                 // bf16 [2][64][1024] c cross-block (slot0 = c0)
#define OFF_BAR   76152832ull                 // u32 [4][64][32]: 1 flag per 128B line
#define N_FLAG_WORDS (4 * 64 * 32)

// Agent-scope relaxed (L1/L2-bypassing, meet-at-L3) accessors — r5/r8-proven.
__device__ __forceinline__ u64 cohload(const u64* p) {
  return __hip_atomic_load(p, __ATOMIC_RELAXED, __HIP_MEMORY_SCOPE_AGENT);
}
__device__ __forceinline__ void cohstore(u64* p, u64 v) {
  __hip_atomic_store(p, v, __ATOMIC_RELAXED, __HIP_MEMORY_SCOPE_AGENT);
}
__device__ __forceinline__ bf16x8 cohload_v8(const bf16* p) {
  union { u64 q[2]; bf16x8 v; } u;
  const u64* q = (const u64*)p;
  u.q[0] = cohload(q);
  u.q[1] = cohload(q + 1);
  return u.v;
}
__device__ __forceinline__ u32x4 cohload_q4(const bf16* p) {
  union { u64 q[2]; u32x4 v; } u;
  const u64* q = (const u64*)p;
  u.q[0] = cohload(q);
  u.q[1] = cohload(q + 1);
  return u.v;
}

// ---------------- prep: weights->bf16, h0/c0 slot0 init, barrier flags=0 ----------------
__global__ void k_prep(const float* __restrict__ wih, const float* __restrict__ whh,
                       const float* __restrict__ wch, const float* __restrict__ wc2h,
                       const float* __restrict__ dw, const float* __restrict__ h0,
                       const float* __restrict__ c0, char* __restrict__ ws) {
  const long N_W = 4194304, N_DW = 65536, N_S = 65536;
  const long TOT = N_W + N_DW + 2 * N_S + N_FLAG_WORDS;
  long stride = (long)gridDim.x * blockDim.x;
  for (long idx = (long)blockIdx.x * blockDim.x + threadIdx.x; idx < TOT; idx += stride) {
    if (idx < N_W) {
      long m = idx >> 20, e = idx & 1048575;
      const float* s = (m == 0) ? wih : (m == 1) ? whh : (m == 2) ? wch : wc2h;
      ((bf16*)(ws + OFF_WIH))[idx] = (bf16)s[e];
    } else if (idx < N_W + N_DW) {
      long j = idx - N_W; long r = j >> 10, e = j & 1023;
      ((bf16*)(ws + OFF_DW))[j] = (bf16)((r < NTAGS) ? dw[r * 1024 + e] : 0.f);
    } else if (idx < N_W + N_DW + N_S) {          // HB slot0 = h0
      long j = idx - N_W - N_DW;
      ((bf16*)(ws + OFF_HB))[j] = (bf16)h0[j];
    } else if (idx < N_W + N_DW + 2 * N_S) {      // CB slot0 = c0
      long j = idx - N_W - N_DW - N_S;
      ((bf16*)(ws + OFF_CB))[j] = (bf16)c0[j];
    } else {                                      // flags = 0 (replay safety)
      long j = idx - N_W - N_DW - 2 * N_S;
      ((u32*)(ws + OFF_BAR))[j] = 0u;
    }
  }
}

// ---------------- XW = emb[X] @ Wih^T + b_ih + b_hh ----------------
// 256 blocks; block = 64 rows. A gathered ONCE into 128 VGPRs of bf16 frags
// (vs 16x re-gather in the old (256,16) grid); inner loop streams B over 16
// column tiles from L2. Numerics identical to the old version.
__global__ __launch_bounds__(256, 1) void k_xw(const int* __restrict__ X,
                                               const float* __restrict__ emb,
                                               const float* __restrict__ b_ih,
                                               const float* __restrict__ b_hh,
                                               char* __restrict__ ws) {
  const bf16* wih = (const bf16*)(ws + OFF_WIH);
  bf16* xw = (bf16*)(ws + OFF_XW);
  int l = threadIdx.x & 63, wv = threadIdx.x >> 6;
  int i0 = blockIdx.x * 64 + wv * 16;
  const float* ap = emb + (long)X[i0 + (l & 15)] * 1024 + ((l >> 4) * 8);

  // A tile (16 rows x K=1024) -> bf16 fragments in registers (32 x bf16x8)
  bf16x8 a_reg[32];
#pragma unroll
  for (int k = 0; k < 32; ++k) {
    f32x4 f0 = *(const f32x4*)(ap + k * 32);
    f32x4 f1 = *(const f32x4*)(ap + k * 32 + 4);
    bf16x8 a;
#pragma unroll
    for (int q = 0; q < 4; ++q) { a[q] = (bf16)f0[q]; a[4 + q] = (bf16)f1[q]; }
    a_reg[k] = a;
  }

  f32x4 zero = {0.f, 0.f, 0.f, 0.f};
  for (int ct = 0; ct < 16; ++ct) {
    int h0 = ct * 64;
    const bf16* bp = wih + (long)(h0 + (l & 15)) * 1024 + ((l >> 4) * 8);
    f32x4 acc[4] = {zero, zero, zero, zero};
#pragma unroll
    for (int k = 0; k < 32; ++k)
#pragma unroll
      for (int j = 0; j < 4; ++j) {
        bf16x8 b = *(const bf16x8*)(bp + j * 16 * 1024 + k * 32);
        acc[j] = __builtin_amdgcn_mfma_f32_16x16x32_bf16(a_reg[k], b, acc[j], 0, 0, 0);
      }
#pragma unroll
    for (int j = 0; j < 4; ++j)
#pragma unroll
      for (int r = 0; r < 4; ++r) {
        int row = i0 + (l >> 4) * 4 + r;
        int col = h0 + j * 16 + (l & 15);
        xw[(long)row * 1024 + col] = (bf16)(acc[j][r] + b_ih[col] + b_hh[col]);
      }
  }
}

// ---------------- recurrence: 4 indep batch-groups x 64 blocks (r8-proven) ----------------
// group g = blockIdx&3 owns batch rows [16g,16g+16); block j = blockIdx>>2 owns h-slice
// [16j,16j+16). 4 waves K-split (256 each).
//  (1) weights pinned in VGPRs with IN-LOOP asm (defeats rematerialization),
//  (2) phase-B c fragments carried in registers into next phase A,
//  (3) histb store tucked between flag-store and poll (hides under the wait).
__global__ __launch_bounds__(256, 1) void k_rnn(const float* __restrict__ b_ch,
                                                const float* __restrict__ b_c2h,
                                                const float* __restrict__ c0,
                                                char* __restrict__ ws) {
  const bf16* xw = (const bf16*)(ws + OFF_XW);
  bf16* histb = (bf16*)(ws + OFF_HISTB);
  bf16* HB = (bf16*)(ws + OFF_HB);
  bf16* CB = (bf16*)(ws + OFF_CB);
  int g = blockIdx.x & 3, j = blockIdx.x >> 2;
  u32* flags = (u32*)(ws + OFF_BAR) + g * 64 * 32;

  int l = threadIdx.x & 63, wv = threadIdx.x >> 6;
  int b0 = g * 16, h0b = j * 16;
  int e = threadIdx.x;
  int eoff = (b0 + (e >> 4)) * 1024 + h0b + (e & 15);
  int gh = h0b + (e & 15);

  __shared__ float red[4][2][256];
  __shared__ bf16 xfer[256];   // 16x16 outgoing tile staging

  int lane_r = l & 15;
  int koff = wv * 256 + ((l >> 4) * 8);
  long arow = (long)(b0 + lane_r) * 1024 + koff;

  // weight fragments -> registers (96 VGPRs of bf16), plus rolling c fragments.
  u32x4 whh_r[8], wch_r[8], wc2h_r[8], cfr[8];
  {
    const bf16* p1 = (const bf16*)(ws + OFF_WHH)  + (long)(h0b + lane_r) * 1024 + koff;
    const bf16* p2 = (const bf16*)(ws + OFF_WCH)  + (long)(h0b + lane_r) * 1024 + koff;
    const bf16* p3 = (const bf16*)(ws + OFF_WC2H) + (long)(h0b + lane_r) * 1024 + koff;
#pragma unroll
    for (int kk = 0; kk < 8; ++kk) {
      whh_r[kk]  = *(const u32x4*)(p1 + kk * 32);
      wch_r[kk]  = *(const u32x4*)(p2 + kk * 32);
      wc2h_r[kk] = *(const u32x4*)(p3 + kk * 32);
      cfr[kk] = cohload_q4(CB + arow + kk * 32);   // c(0) from slot0
    }
  }

  float bch_v = b_ch[gh], bc2h_v = b_c2h[gh];
  float c_reg = c0[eoff];
  f32x4 zero = {0.f, 0.f, 0.f, 0.f};

  for (int t = 0; t < TT; ++t) {
    // In-loop pins: the empty asm "modifies" the frags every iteration, so the
    // compiler must keep them resident (cannot re-load from memory).
    asm volatile("" : "+v"(whh_r[0]), "+v"(whh_r[1]), "+v"(whh_r[2]), "+v"(whh_r[3]),
                      "+v"(whh_r[4]), "+v"(whh_r[5]), "+v"(whh_r[6]), "+v"(whh_r[7]),
                      "+v"(wch_r[0]), "+v"(wch_r[1]), "+v"(wch_r[2]), "+v"(wch_r[3]),
                      "+v"(wch_r[4]), "+v"(wch_r[5]), "+v"(wch_r[6]), "+v"(wch_r[7]));
    asm volatile("" : "+v"(wc2h_r[0]), "+v"(wc2h_r[1]), "+v"(wc2h_r[2]), "+v"(wc2h_r[3]),
                      "+v"(wc2h_r[4]), "+v"(wc2h_r[5]), "+v"(wc2h_r[6]), "+v"(wc2h_r[7]));
    asm volatile("" : "+v"(cfr[0]), "+v"(cfr[1]), "+v"(cfr[2]), "+v"(cfr[3]),
                      "+v"(cfr[4]), "+v"(cfr[5]), "+v"(cfr[6]), "+v"(cfr[7]));

    long slot1 = (long)((t + 1) & 1) * 65536;
    float xwv = (float)xw[(long)t * 65536 + eoff];
    u32 tkA = 2u * t + 1u, tkB = 2u * t + 2u;
    const bf16* hx = HB + (long)(t & 1) * 65536;

    // ---- phase A: pre = h(t)@Whh (+xw), cg = c(t)@Wch (c frags already in regs)
    f32x4 ap_ = zero, ac_ = zero;
#pragma unroll
    for (int kk = 0; kk < 8; ++kk) {
      bf16x8 a1 = cohload_v8(hx + arow + kk * 32);
      ap_ = __builtin_amdgcn_mfma_f32_16x16x32_bf16(
          a1, __builtin_bit_cast(bf16x8, whh_r[kk]), ap_, 0, 0, 0);
      ac_ = __builtin_amdgcn_mfma_f32_16x16x32_bf16(
          __builtin_bit_cast(bf16x8, cfr[kk]), __builtin_bit_cast(bf16x8, wch_r[kk]), ac_, 0, 0, 0);
    }
#pragma unroll
    for (int r = 0; r < 4; ++r) {
      int ei = ((l >> 4) * 4 + r) * 16 + (l & 15);
      red[wv][0][ei] = ap_[r];
      red[wv][1][ei] = ac_[r];
    }
    __syncthreads();
    float pre = red[0][0][e] + red[1][0][e] + red[2][0][e] + red[3][0][e] + xwv;
    float cgm = red[0][1][e] + red[1][1][e] + red[2][1][e] + red[3][1][e] + bch_v;
    float gif = 1.f / (1.f + expf(-(pre + cgm)));
    float cy = gif * (c_reg + tanhf(pre));
    c_reg = cy;
    xfer[e] = (bf16)cy;
    __syncthreads();                    // xfer ready; red reads done
    if (e < 64)
      cohstore((u64*)(CB + slot1 + (long)(b0 + (e >> 2)) * 1024 + h0b) + (e & 3),
               ((u64*)xfer)[e]);
    asm volatile("s_waitcnt vmcnt(0)" ::: "memory");   // tile stores ack'd @L3
    if (e == 0)
      __hip_atomic_store(&flags[j * 32], tkA, __ATOMIC_RELAXED, __HIP_MEMORY_SCOPE_AGENT);
    if (e < 64) {
      const u32* my = &flags[e * 32];
      while (!__all(__hip_atomic_load(my, __ATOMIC_RELAXED, __HIP_MEMORY_SCOPE_AGENT) >= tkA))
        __builtin_amdgcn_s_sleep(1);
    }
    asm volatile("" ::: "memory");
    __syncthreads();

    // ---- phase B: o = cy(t+1)@Wc2h; keep cy frags for next step's phase A
    f32x4 ao = zero;
#pragma unroll
    for (int kk = 0; kk < 8; ++kk) {
      cfr[kk] = cohload_q4(CB + slot1 + arow + kk * 32);
      ao = __builtin_amdgcn_mfma_f32_16x16x32_bf16(
          __builtin_bit_cast(bf16x8, cfr[kk]), __builtin_bit_cast(bf16x8, wc2h_r[kk]), ao, 0, 0, 0);
    }
#pragma unroll
    for (int r = 0; r < 4; ++r)
      red[wv][0][((l >> 4) * 4 + r) * 16 + (l & 15)] = ao[r];
    __syncthreads();
    float o = red[0][0][e] + red[1][0][e] + red[2][0][e] + red[3][0][e] + bc2h_v;
    float og = 1.f / (1.f + expf(-(pre + o)));
    bf16 hb = (bf16)(og * tanhf(cy));
    xfer[e] = hb;
    __syncthreads();
    if (t < TT - 1) {
      if (e < 64)
        cohstore((u64*)(HB + slot1 + (long)(b0 + (e >> 2)) * 1024 + h0b) + (e & 3),
                 ((u64*)xfer)[e]);
      asm volatile("s_waitcnt vmcnt(0)" ::: "memory");
      if (e == 0)
        __hip_atomic_store(&flags[j * 32], tkB, __ATOMIC_RELAXED, __HIP_MEMORY_SCOPE_AGENT);
      histb[(long)t * 65536 + eoff] = hb;   // fire-and-forget; hides under the poll
      if (e < 64) {
        const u32* my = &flags[e * 32];
        while (!__all(__hip_atomic_load(my, __ATOMIC_RELAXED, __HIP_MEMORY_SCOPE_AGENT) >= tkB))
          __builtin_amdgcn_s_sleep(1);
      }
      asm volatile("" ::: "memory");
      __syncthreads();
    } else {
      histb[(long)t * 65536 + eoff] = hb;
    }
  }
}

// ---------------- dense + softmax ----------------
__global__ __launch_bounds__(256) void k_out(const float* __restrict__ dense_b,
                                             const char* __restrict__ ws,
                                             float* __restrict__ out) {
  const bf16* h  = (const bf16*)(ws + OFF_HISTB);  // slot t = hy at step t
  const bf16* dw = (const bf16*)(ws + OFF_DW);
  int l = threadIdx.x & 63, wv = threadIdx.x >> 6;
  int i0 = blockIdx.x * 64 + wv * 16;
  const bf16* ap = h  + (long)(i0 + (l & 15)) * 1024 + ((l >> 4) * 8);
  const bf16* bp = dw + (long)(l & 15) * 1024 + ((l >> 4) * 8);
  f32x4 zero = {0.f, 0.f, 0.f, 0.f};
  f32x4 acc[4] = {zero, zero, zero, zero};
  for (int k = 0; k < 1024; k += 32) {
    bf16x8 a = *(const bf16x8*)(ap + k);
#pragma unroll
    for (int j = 0; j < 4; ++j) {
      bf16x8 b = *(const bf16x8*)(bp + j * 16 * 1024 + k);
      acc[j] = __builtin_amdgcn_mfma_f32_16x16x32_bf16(a, b, acc[j], 0, 0, 0);
    }
  }
  int tag0 = l & 15;
#pragma unroll
  for (int r = 0; r < 4; ++r) {
    int row = i0 + (l >> 4) * 4 + r;
    float lg[4], ex[4];
    float mx = -1e30f;
#pragma unroll
    for (int j = 0; j < 4; ++j) {
      int tag = j * 16 + tag0;
      lg[j] = (tag < NTAGS) ? (acc[j][r] + dense_b[tag]) : -1e30f;
      mx = fmaxf(mx, lg[j]);
    }
    for (int m = 1; m < 16; m <<= 1) mx = fmaxf(mx, __shfl_xor(mx, m, 64));
    float s = 0.f;
#pragma unroll
    for (int j = 0; j < 4; ++j) {
      int tag = j * 16 + tag0;
      ex[j] = (tag < NTAGS) ? expf(lg[j] - mx) : 0.f;
      s += ex[j];
    }
    for (int m = 1; m < 16; m <<= 1) s += __shfl_xor(s, m, 64);
    float inv = 1.f / s;
#pragma unroll
    for (int j = 0; j < 4; ++j) {
      int tag = j * 16 + tag0;
      if (tag < NTAGS) out[(long)row * 50 + tag] = ex[j] * inv;
    }
  }
}

extern "C" void kernel_launch(void* const* d_in, const int* in_sizes, int n_in,
                              void* d_out, int out_size, void* d_ws, size_t ws_size,
                              hipStream_t stream) {
  const int*   X        = (const int*)d_in[0];
  // d_in[1] = lengths (unused; all == T)
  const float* embedding = (const float*)d_in[2];
  const float* w_ih  = (const float*)d_in[3];
  const float* w_hh  = (const float*)d_in[4];
  const float* w_ch  = (const float*)d_in[5];
  const float* w_c2h = (const float*)d_in[6];
  const float* b_ih  = (const float*)d_in[7];
  const float* b_hh  = (const float*)d_in[8];
  const float* b_ch  = (const float*)d_in[9];
  const float* b_c2h = (const float*)d_in[10];
  const float* dense_w = (const float*)d_in[11];
  const float* dense_b = (const float*)d_in[12];
  const float* h0 = (const float*)d_in[13];
  const float* c0 = (const float*)d_in[14];
  char* ws = (char*)d_ws;
  float* out = (float*)d_out;

  k_prep<<<2048, 256, 0, stream>>>(w_ih, w_hh, w_ch, w_c2h, dense_w, h0, c0, ws);
  k_xw<<<256, 256, 0, stream>>>(X, embedding, b_ih, b_hh, ws);

  void* args[] = {(void*)&b_ch, (void*)&b_c2h, (void*)&c0, (void*)&ws};
  hipLaunchCooperativeKernel((const void*)k_rnn, dim3(256), dim3(256), args, 0, stream);

  k_out<<<256, 256, 0, stream>>>(dense_b, ws, out);
}